// Round 8
// baseline (254.212 us; speedup 1.0000x reference)
//
#include <hip/hip_runtime.h>
#include <hip/hip_bf16.h>
#include <stdint.h>
#include <stddef.h>

// ContrastiveLoss: N=4096, D=768.
// loss = mean_{ij} (1-g)*d2 + g*max(2-sqrt(d2),0)^2,
// d2 = sa[i]+sb[j]-2*dot(i,j)+2e-6*(ra[i]-rb[j])+768e-12 (clamped at 0).
// R7: MX-scaled fp8 MFMA (16x16x128 f8f6f4, unit scales = exact fp8 math,
//     2x rate / 4x fewer MFMA ops vs plain fp8). Linear fp8 layout (any
//     k-permutation shared by A and B preserves the dot, so lane k-chunking
//     is self-consistent). C/D layout is shape-determined -> epilogue
//     unchanged. launch_bounds(256,3): ~145 live regs needs >128 cap.
// Lesson log: R4 32x32 frags = structural 4-way LDS conflict; R3 dbuf and
//     dup-epilogue = spill (WRITE_SIZE is the detector); R2/R6 LDS algebra
//     (16 rows x consecutive 16-B chunks, XOR-8 over rows, b128) = 0 conflict.

#define NROWS 4096
#define DIM   768
#define BM    128
#define BN    128
#define BKE   128              // K elements per tile (128-B fp8 LDS rows)
#define MARGIN 2.0f
#define EPSV   1e-6f

typedef float f32x4 __attribute__((ext_vector_type(4)));
typedef int   i32x4 __attribute__((ext_vector_type(4)));
typedef int   i32x8 __attribute__((ext_vector_type(8)));
typedef unsigned long long u64;
typedef unsigned char fp8_t;

// ---------------- prologue: prep (2048 blocks) + pack (8192 blocks) --------
__global__ __launch_bounds__(256) void prologue_kernel(
    const float* __restrict__ A, const float* __restrict__ B,
    const int* __restrict__ gt,
    fp8_t* __restrict__ Af8, fp8_t* __restrict__ Bf8,
    float* __restrict__ sa, float* __restrict__ sb,
    float* __restrict__ ra, float* __restrict__ rb,
    u64* __restrict__ gtp, float* __restrict__ out)
{
    const int tid  = threadIdx.x;
    const int wave = tid >> 6;
    const int lane = tid & 63;
    const int bx   = blockIdx.x;

    if (bx == 0 && tid == 0) out[0] = 0.0f;

    if (bx < 2048) {
        // ---- prep: fp8 e4m3 cast (linear) + exact fp32 row sums/sumsq ----
        const int isB  = bx >= 1024;
        const int row  = (bx & 1023) * 4 + wave;
        const float* X = isB ? B : A;
        fp8_t* Xb      = isB ? Bf8 : Af8;
        float* sdst    = isB ? sb : sa;
        float* rdst    = isB ? rb : ra;

        const float4* xr = (const float4*)(X + (size_t)row * DIM);
        unsigned int* xb = (unsigned int*)(Xb + (size_t)row * DIM);

        float sum = 0.0f, sq = 0.0f;
        #pragma unroll
        for (int jb = 0; jb < 3; ++jb) {
            float4 v = xr[lane + 64 * jb];
            int pk = 0;
            pk = __builtin_amdgcn_cvt_pk_fp8_f32(v.x, v.y, pk, false);
            pk = __builtin_amdgcn_cvt_pk_fp8_f32(v.z, v.w, pk, true);
            xb[lane + 64 * jb] = (unsigned int)pk;
            sum += (v.x + v.y) + (v.z + v.w);
            sq  += v.x * v.x + v.y * v.y + v.z * v.z + v.w * v.w;
        }
        #pragma unroll
        for (int off = 32; off > 0; off >>= 1) {
            sum += __shfl_down(sum, off);
            sq  += __shfl_down(sq,  off);
        }
        if (lane == 0) { rdst[row] = sum; sdst[row] = sq; }
    } else {
        // ---- pack: gt int32 -> u64 bitmask per 64-col block ----
        const int wid = (bx - 2048) * 4 + wave;
        const size_t base = (size_t)wid * 8;
        int v[8];
        #pragma unroll
        for (int i = 0; i < 8; ++i)
            v[i] = gt[base * 64 + (size_t)i * 64 + lane];
        u64 mine = 0;
        #pragma unroll
        for (int i = 0; i < 8; ++i) {
            const u64 m = __ballot(v[i] != 0);
            if (lane == i) mine = m;
        }
        if (lane < 8) gtp[base + lane] = mine;
    }
}

// ---------------- fused GEMM + loss (MX fp8, unit scales) -------------------
// 128x128 tile / 256 threads (4 waves x 64x64 = 4x4 of 16x16x128 MFMA).
// BKE=128 (one MFMA K-window per tile), single-buffered 32 KB LDS, proven
// 2-barrier K-loop, XOR-8 staging swizzle. Lane (fr=lane&15, q=lane>>4):
// A row fr, k-bytes [32q,32q+32) = chunks 2q,2q+1 (de-swizzled, b128 pairs —
// 2-way bank aliasing only = free). C/D: col=lane&15, row=(lane>>4)*4+reg.
__global__ __launch_bounds__(256, 3) void loss_kernel(
    const fp8_t* __restrict__ A, const fp8_t* __restrict__ B,
    const float* __restrict__ sa, const float* __restrict__ sb,
    const float* __restrict__ ra, const float* __restrict__ rb,
    const uint2* __restrict__ gtp, float* __restrict__ out)
{
    __shared__ __align__(16) fp8_t As[BM * BKE];  // 16 KB
    __shared__ __align__(16) fp8_t Bs[BN * BKE];  // 16 KB

    const int tid  = threadIdx.x;
    const int wave = tid >> 6;
    const int lane = tid & 63;
    const int m0 = blockIdx.y * BM;
    const int n0 = blockIdx.x * BN;

    f32x4 acc[4][4] = {};

    const int fr = lane & 15;            // frag row (A) / frag col (B)
    const int q  = lane >> 4;            // k-quarter (32 B each)
    const int wm = (wave >> 1) * 64;
    const int wn = (wave & 1) * 64;

    // staging: chunk c (16 B) -> row c>>3, slot c&7; LDS slot p of row holds
    // global chunk p ^ (row&7)   [XOR-8 swizzle]
    const int srow = lane >> 3;
    const int sp   = lane & 7;

    for (int k0 = 0; k0 < DIM; k0 += BKE) {
        __syncthreads();   // prev iter's LDS reads done
        #pragma unroll
        for (int j = 0; j < 4; ++j) {          // A: 1024 chunks, 256/wave
            const int c0  = wave * 256 + j * 64;            // wave-uniform
            const int row = (c0 >> 3) + srow;
            const int gcx = sp ^ (row & 7);
            const fp8_t* ga = A + (size_t)(m0 + row) * DIM + k0 + gcx * 16;
            __builtin_amdgcn_global_load_lds(
                (const __attribute__((address_space(1))) void*)ga,
                (__attribute__((address_space(3))) void*)(As + c0 * 16),
                16, 0, 0);
        }
        #pragma unroll
        for (int j = 0; j < 4; ++j) {          // B: 1024 chunks, 256/wave
            const int c0  = wave * 256 + j * 64;
            const int row = (c0 >> 3) + srow;
            const int gcx = sp ^ (row & 7);
            const fp8_t* gb = B + (size_t)(n0 + row) * DIM + k0 + gcx * 16;
            __builtin_amdgcn_global_load_lds(
                (const __attribute__((address_space(1))) void*)gb,
                (__attribute__((address_space(3))) void*)(Bs + c0 * 16),
                16, 0, 0);
        }
        __syncthreads();   // staging complete

        // A fragments: lane's 32 k-bytes = de-swizzled chunks 2q, 2q+1
        i32x8 af[4];
        #pragma unroll
        for (int i = 0; i < 4; ++i) {
            const int ar = wm + i * 16 + fr;
            const i32x4 lo = *(const i32x4*)(As + ar * BKE + (((2 * q)     ^ (ar & 7)) * 16));
            const i32x4 hi = *(const i32x4*)(As + ar * BKE + (((2 * q + 1) ^ (ar & 7)) * 16));
            af[i] = (i32x8){lo[0], lo[1], lo[2], lo[3], hi[0], hi[1], hi[2], hi[3]};
        }
        // stream B fragments one at a time to cap register liveness
        #pragma unroll
        for (int ni = 0; ni < 4; ++ni) {
            const int br = wn + ni * 16 + fr;
            const i32x4 lo = *(const i32x4*)(Bs + br * BKE + (((2 * q)     ^ (br & 7)) * 16));
            const i32x4 hi = *(const i32x4*)(Bs + br * BKE + (((2 * q + 1) ^ (br & 7)) * 16));
            const i32x8 bf = (i32x8){lo[0], lo[1], lo[2], lo[3], hi[0], hi[1], hi[2], hi[3]};
            #pragma unroll
            for (int mi = 0; mi < 4; ++mi)
                acc[mi][ni] = __builtin_amdgcn_mfma_scale_f32_16x16x128_f8f6f4(
                    af[mi], bf, acc[mi][ni],
                    0, 0,                       // cbsz=fp8 e4m3, blgp=fp8 e4m3
                    0, 0x7F7F7F7F,              // scale_a opsel, e8m0 x1.0
                    0, 0x7F7F7F7F);             // scale_b opsel, e8m0 x1.0
        }
    }

    // ---- fused epilogue: C/D col=lane&15, row=(lane>>4)*4+reg ----
    // Single traversal; per-element exact-correction branch (never taken for
    // this data: min d2 ~ 1250 >> 4) — no dup loop, no spill trigger.
    const int cq = lane & 15;
    const int rq = (lane >> 4) * 4;
    const int cb = (n0 + wn) >> 6;

    float cc[4];
    #pragma unroll
    for (int ni = 0; ni < 4; ++ni) {
        const int col = n0 + wn + ni * 16 + cq;
        cc[ni] = sb[col] - 2.0f * EPSV * rb[col];
    }

    float local = 0.0f;
    #pragma unroll
    for (int mi = 0; mi < 4; ++mi) {
        #pragma unroll
        for (int rr = 0; rr < 4; ++rr) {
            const int row = m0 + wm + mi * 16 + rq + rr;
            const float crr = sa[row] + 2.0f * EPSV * ra[row]
                            + (float)DIM * EPSV * EPSV;
            const uint2 w = gtp[(size_t)row * (NROWS / 64) + cb];
            #pragma unroll
            for (int ni = 0; ni < 4; ++ni) {
                const float d2 = (crr + cc[ni]) - 2.0f * acc[mi][ni][rr];
                const unsigned wd = (ni < 2) ? w.x : w.y;
                const float gf = (float)((wd >> (cq + (ni & 1) * 16)) & 1u);
                float contrib = d2 - gf * d2;           // hinge==0 fast path
                if (__builtin_expect(d2 < 4.0f, 0)) {   // exact, never taken
                    const float d2c  = fmaxf(d2, 0.0f);
                    const float dist = sqrtf(d2c);
                    const float h    = fmaxf(MARGIN - dist, 0.0f);
                    contrib = (1.0f - gf) * d2c + gf * h * h;
                }
                local += contrib;
            }
        }
    }

    #pragma unroll
    for (int off = 32; off > 0; off >>= 1) local += __shfl_down(local, off);

    float* redp = (float*)As;   // reuse LDS for block reduction
    __syncthreads();
    if (lane == 0) redp[wave] = local;
    __syncthreads();
    if (tid == 0) {
        const float s = (redp[0] + redp[1]) + (redp[2] + redp[3]);
        atomicAdd(out, s * (1.0f / (4096.0f * 4096.0f)));
    }
}

// ---------------------------------------------------------------------------
extern "C" void kernel_launch(void* const* d_in, const int* in_sizes, int n_in,
                              void* d_out, int out_size, void* d_ws, size_t ws_size,
                              hipStream_t stream)
{
    const float* A  = (const float*)d_in[0];
    const float* B  = (const float*)d_in[1];
    const int*   gt = (const int*)d_in[2];
    float* out = (float*)d_out;

    char* ws = (char*)d_ws;
    const size_t NB8 = (size_t)NROWS * DIM;   // 3,145,728 B per fp8 matrix
    fp8_t* Af8 = (fp8_t*)(ws);
    fp8_t* Bf8 = (fp8_t*)(ws + NB8);
    float* sa = (float*)(ws + 2 * NB8);
    float* sb = (float*)(ws + 2 * NB8 + 16384);
    float* ra = (float*)(ws + 2 * NB8 + 32768);
    float* rb = (float*)(ws + 2 * NB8 + 49152);
    u64* gtp  = (u64*)(ws + 2 * NB8 + 65536); // 2 MB

    prologue_kernel<<<dim3(10240), 256, 0, stream>>>(
        A, B, gt, Af8, Bf8, sa, sb, ra, rb, gtp, out);
    loss_kernel<<<dim3(NROWS / BN, NROWS / BM), 256, 0, stream>>>(
        Af8, Bf8, sa, sb, ra, rb, (const uint2*)gtp, out);
}

// Round 9
// 136.511 us; speedup vs baseline: 1.8622x; 1.8622x over previous
//
#include <hip/hip_runtime.h>
#include <hip/hip_bf16.h>
#include <stdint.h>
#include <stddef.h>

// ContrastiveLoss: N=4096, D=768.
// loss = mean_{ij} (1-g)*d2 + g*max(2-sqrt(d2),0)^2,
// d2 = sa[i]+sb[j]-2*dot(i,j)+2e-6*(ra[i]-rb[j])+768e-12 (clamped at 0).
// R8: exact revert to R6 — the verified best (135.5 µs total; loss_kernel
//     ~25 µs, 0 conflicts, 0 spill). fp8 e4m3 GEMM, k-permuted global
//     layout replicating R2's proven conflict-free LDS algebra, single-pass
//     epilogue with rare-branch exact correction.
// Lesson log (structural, do not retry):
//   - R3: LDS double-buffer @ (256,4) -> scratch spill (WRITE_SIZE 100 MB).
//   - R4: 32x32 MFMA frag pattern -> structural 4-way LDS conflict.
//   - R5: b64 frag reads @ 32-B granule stride -> 4-way conflict again.
//   - R7: mfma_scale_f32_16x16x128_f8f6f4 from HIP -> allocator caps VGPRs
//         at 84, acc+frags live in scratch, 570 MB/launch scratch traffic.
//   - WRITE_SIZE is the spill detector; only the R2/R6 LDS read algebra
//     (16 rows x consecutive 16-B chunks, XOR-8 over rows, b128) is clean.

#define NROWS 4096
#define DIM   768
#define BM    128
#define BN    128
#define BKE   128              // K elements per tile (128 B fp8 rows)
#define MARGIN 2.0f
#define EPSV   1e-6f

typedef float f32x4 __attribute__((ext_vector_type(4)));
typedef long  lng2  __attribute__((ext_vector_type(2)));
typedef unsigned long long u64;
typedef unsigned char fp8_t;

// Permutation of each 128-elem k-segment, baked into the fp8 global layout:
// element (kk,q,j) [kk=K32-window 0..3, q=quad 0..3, j=0..7] is stored at
// byte ((kk>>1)*4 + q)*16 + (kk&1)*8 + j. Both A and B use it => dot
// products are unchanged (same k-order on both operands).

// ---------------- prologue: prep (2048 blocks) + pack (8192 blocks) --------
__global__ __launch_bounds__(256) void prologue_kernel(
    const float* __restrict__ A, const float* __restrict__ B,
    const int* __restrict__ gt,
    fp8_t* __restrict__ Af8, fp8_t* __restrict__ Bf8,
    float* __restrict__ sa, float* __restrict__ sb,
    float* __restrict__ ra, float* __restrict__ rb,
    u64* __restrict__ gtp, float* __restrict__ out)
{
    const int tid  = threadIdx.x;
    const int wave = tid >> 6;
    const int lane = tid & 63;
    const int bx   = blockIdx.x;

    if (bx == 0 && tid == 0) out[0] = 0.0f;

    if (bx < 2048) {
        // ---- prep: fp8 cast (k-permuted) + exact fp32 row sums/sumsq ----
        const int isB  = bx >= 1024;
        const int row  = (bx & 1023) * 4 + wave;
        const float* X = isB ? B : A;
        fp8_t* Xb      = isB ? Bf8 : Af8;
        float* sdst    = isB ? sb : sa;
        float* rdst    = isB ? rb : ra;

        const float4* xr = (const float4*)(X + (size_t)row * DIM);
        unsigned int* xb = (unsigned int*)(Xb + (size_t)row * DIM);

        float sum = 0.0f, sq = 0.0f;
        #pragma unroll
        for (int jb = 0; jb < 3; ++jb) {
            float4 v = xr[lane + 64 * jb];
            int pk = 0;
            pk = __builtin_amdgcn_cvt_pk_fp8_f32(v.x, v.y, pk, false);
            pk = __builtin_amdgcn_cvt_pk_fp8_f32(v.z, v.w, pk, true);
            // permuted destination dword
            const int e4  = lane + 64 * jb;     // source dword idx in row
            const int seg = e4 >> 5;            // 128-elem segment
            const int e   = (e4 & 31) * 4;      // elem within segment
            const int kk  = e >> 5;
            const int q   = (e >> 3) & 3;
            const int jj  = e & 7;              // 0 or 4
            const int pos = ((kk >> 1) * 4 + q) * 16 + (kk & 1) * 8 + jj;
            xb[seg * 32 + (pos >> 2)] = (unsigned int)pk;
            sum += (v.x + v.y) + (v.z + v.w);
            sq  += v.x * v.x + v.y * v.y + v.z * v.z + v.w * v.w;
        }
        #pragma unroll
        for (int off = 32; off > 0; off >>= 1) {
            sum += __shfl_down(sum, off);
            sq  += __shfl_down(sq,  off);
        }
        if (lane == 0) { rdst[row] = sum; sdst[row] = sq; }
    } else {
        // ---- pack: gt int32 -> u64 bitmask per 64-col block ----
        const int wid = (bx - 2048) * 4 + wave;
        const size_t base = (size_t)wid * 8;
        int v[8];
        #pragma unroll
        for (int i = 0; i < 8; ++i)
            v[i] = gt[base * 64 + (size_t)i * 64 + lane];
        u64 mine = 0;
        #pragma unroll
        for (int i = 0; i < 8; ++i) {
            const u64 m = __ballot(v[i] != 0);
            if (lane == i) mine = m;
        }
        if (lane < 8) gtp[base + lane] = mine;
    }
}

// ---------------- fused GEMM + loss (fp8 e4m3, k-permuted layout) ----------
// 128x128 tile / 256 threads (4 waves x 64x64 of 4x4 16x16x32 fp8 MFMA).
// BKE=128 (128-B LDS rows), single-buffered 32 KB LDS, 2-barrier K-loop.
// Frag reads: b128 at chunk c = kk2*4 + q, slot (c ^ (row&7)) — R2's
// measured-conflict-free algebra. Each b128 = windows 2*kk2 (lo 8 B) and
// 2*kk2+1 (hi 8 B).
__global__ __launch_bounds__(256, 4) void loss_kernel(
    const fp8_t* __restrict__ A, const fp8_t* __restrict__ B,
    const float* __restrict__ sa, const float* __restrict__ sb,
    const float* __restrict__ ra, const float* __restrict__ rb,
    const uint2* __restrict__ gtp, float* __restrict__ out)
{
    __shared__ __align__(16) fp8_t As[BM * BKE];  // 16 KB
    __shared__ __align__(16) fp8_t Bs[BN * BKE];  // 16 KB

    const int tid  = threadIdx.x;
    const int wave = tid >> 6;
    const int lane = tid & 63;
    const int m0 = blockIdx.y * BM;
    const int n0 = blockIdx.x * BN;

    f32x4 acc[4][4] = {};

    const int fr = lane & 15;            // frag row (A) / frag col (B)
    const int q  = lane >> 4;            // quad
    const int wm = (wave >> 1) * 64;
    const int wn = (wave & 1) * 64;

    // staging: chunk c (16 B) -> row c>>3, slot c&7; LDS slot p of row holds
    // global chunk p ^ (row&7)   [XOR-8 swizzle]
    const int srow = lane >> 3;
    const int sp   = lane & 7;

    for (int k0 = 0; k0 < DIM; k0 += BKE) {
        __syncthreads();   // prev iter's LDS reads done
        #pragma unroll
        for (int j = 0; j < 4; ++j) {          // A: 1024 chunks, 256/wave
            const int c0  = wave * 256 + j * 64;            // wave-uniform
            const int row = (c0 >> 3) + srow;
            const int gcx = sp ^ (row & 7);
            const fp8_t* ga = A + (size_t)(m0 + row) * DIM + k0 + gcx * 16;
            __builtin_amdgcn_global_load_lds(
                (const __attribute__((address_space(1))) void*)ga,
                (__attribute__((address_space(3))) void*)(As + c0 * 16),
                16, 0, 0);
        }
        #pragma unroll
        for (int j = 0; j < 4; ++j) {          // B: 1024 chunks, 256/wave
            const int c0  = wave * 256 + j * 64;
            const int row = (c0 >> 3) + srow;
            const int gcx = sp ^ (row & 7);
            const fp8_t* gb = B + (size_t)(n0 + row) * DIM + k0 + gcx * 16;
            __builtin_amdgcn_global_load_lds(
                (const __attribute__((address_space(1))) void*)gb,
                (__attribute__((address_space(3))) void*)(Bs + c0 * 16),
                16, 0, 0);
        }
        __syncthreads();   // staging complete

        #pragma unroll
        for (int kk2 = 0; kk2 < 2; ++kk2) {    // each step: 2 K=32 windows
            const int c = kk2 * 4 + q;         // consecutive chunk per quad
            lng2 ap[4], bp[4];
            #pragma unroll
            for (int i = 0; i < 4; ++i) {
                const int ar = wm + i * 16 + fr;
                const int br = wn + i * 16 + fr;
                ap[i] = *(const lng2*)(As + ar * BKE + ((c ^ (ar & 7)) * 16));
                bp[i] = *(const lng2*)(Bs + br * BKE + ((c ^ (br & 7)) * 16));
            }
            #pragma unroll
            for (int mi = 0; mi < 4; ++mi)
                #pragma unroll
                for (int ni = 0; ni < 4; ++ni)
                    acc[mi][ni] = __builtin_amdgcn_mfma_f32_16x16x32_fp8_fp8(
                        ap[mi][0], bp[ni][0], acc[mi][ni], 0, 0, 0);
            #pragma unroll
            for (int mi = 0; mi < 4; ++mi)
                #pragma unroll
                for (int ni = 0; ni < 4; ++ni)
                    acc[mi][ni] = __builtin_amdgcn_mfma_f32_16x16x32_fp8_fp8(
                        ap[mi][1], bp[ni][1], acc[mi][ni], 0, 0, 0);
        }
    }

    // ---- fused epilogue: C/D col=lane&15, row=(lane>>4)*4+reg ----
    // Single traversal; per-element exact correction branch (never taken for
    // this data: min d2 ~ 1250 >> 4) — no dup loop, no spill trigger.
    const int cq = lane & 15;
    const int rq = (lane >> 4) * 4;
    const int cb = (n0 + wn) >> 6;

    float cc[4];
    #pragma unroll
    for (int ni = 0; ni < 4; ++ni) {
        const int col = n0 + wn + ni * 16 + cq;
        cc[ni] = sb[col] - 2.0f * EPSV * rb[col];
    }

    float local = 0.0f;
    #pragma unroll
    for (int mi = 0; mi < 4; ++mi) {
        #pragma unroll
        for (int rr = 0; rr < 4; ++rr) {
            const int row = m0 + wm + mi * 16 + rq + rr;
            const float crr = sa[row] + 2.0f * EPSV * ra[row]
                            + (float)DIM * EPSV * EPSV;
            const uint2 w = gtp[(size_t)row * (NROWS / 64) + cb];
            #pragma unroll
            for (int ni = 0; ni < 4; ++ni) {
                const float d2 = (crr + cc[ni]) - 2.0f * acc[mi][ni][rr];
                const unsigned wd = (ni < 2) ? w.x : w.y;
                const float gf = (float)((wd >> (cq + (ni & 1) * 16)) & 1u);
                float contrib = d2 - gf * d2;           // hinge==0 fast path
                if (__builtin_expect(d2 < 4.0f, 0)) {   // exact, never taken
                    const float d2c  = fmaxf(d2, 0.0f);
                    const float dist = sqrtf(d2c);
                    const float h    = fmaxf(MARGIN - dist, 0.0f);
                    contrib = (1.0f - gf) * d2c + gf * h * h;
                }
                local += contrib;
            }
        }
    }

    #pragma unroll
    for (int off = 32; off > 0; off >>= 1) local += __shfl_down(local, off);

    float* redp = (float*)As;   // reuse LDS for block reduction
    __syncthreads();
    if (lane == 0) redp[wave] = local;
    __syncthreads();
    if (tid == 0) {
        const float s = (redp[0] + redp[1]) + (redp[2] + redp[3]);
        atomicAdd(out, s * (1.0f / (4096.0f * 4096.0f)));
    }
}

// ---------------------------------------------------------------------------
extern "C" void kernel_launch(void* const* d_in, const int* in_sizes, int n_in,
                              void* d_out, int out_size, void* d_ws, size_t ws_size,
                              hipStream_t stream)
{
    const float* A  = (const float*)d_in[0];
    const float* B  = (const float*)d_in[1];
    const int*   gt = (const int*)d_in[2];
    float* out = (float*)d_out;

    char* ws = (char*)d_ws;
    const size_t NB8 = (size_t)NROWS * DIM;   // 3,145,728 B per fp8 matrix
    fp8_t* Af8 = (fp8_t*)(ws);
    fp8_t* Bf8 = (fp8_t*)(ws + NB8);
    float* sa = (float*)(ws + 2 * NB8);
    float* sb = (float*)(ws + 2 * NB8 + 16384);
    float* ra = (float*)(ws + 2 * NB8 + 32768);
    float* rb = (float*)(ws + 2 * NB8 + 49152);
    u64* gtp  = (u64*)(ws + 2 * NB8 + 65536); // 2 MB

    prologue_kernel<<<dim3(10240), 256, 0, stream>>>(
        A, B, gt, Af8, Bf8, sa, sb, ra, rb, gtp, out);
    loss_kernel<<<dim3(NROWS / BN, NROWS / BM), 256, 0, stream>>>(
        Af8, Bf8, sa, sb, ra, rb, (const uint2*)gtp, out);
}